// Round 6
// baseline (316.473 us; speedup 1.0000x reference)
//
#include <hip/hip_runtime.h>
#include <math.h>

// GCN 2-layer: out = relu( relu( (A @ x) @ W1 + b1 ) @ W2 + b2 )
// A = D^-1/2 (Adj + I) D^-1/2 (weighted, self-loop weight 1).
// Aggregation at d_in=128 ((A@x)@W1 == A@(x@W1), linearity).
// R6: gather fused into MLP (y never hits HBM; bf16 hi/lo straight to
// swizzled LDS); cursor array dropped (scatter bumps offsets, consumer
// uses end-counts); wprep merged into init. 7 launches (was 9).

typedef __attribute__((ext_vector_type(8))) short short8v;   // 8 bf16 = 4 VGPR
typedef __attribute__((ext_vector_type(4))) float floatx4;   // MFMA C/D

__device__ __forceinline__ short f2bf(float f) {             // RNE f32->bf16
    unsigned u = __builtin_bit_cast(unsigned, f);
    unsigned r = (u + 0x7FFFu + ((u >> 16) & 1u)) >> 16;
    return (short)r;
}
__device__ __forceinline__ float bf2f(short s) {
    return __builtin_bit_cast(float, ((unsigned)(unsigned short)s) << 16);
}

// ---------------- init + weight prep (merged) ----------------
// i < N: counts=0, deg=1.  i < 65536: W1t transpose+cvt.  else W2t.
__global__ __launch_bounds__(256) void k_initprep(int* __restrict__ counts,
                                                  float* __restrict__ deg, int n,
                                                  const float* __restrict__ W1,
                                                  const float* __restrict__ W2,
                                                  short* __restrict__ W1t,
                                                  short* __restrict__ W2t) {
    int i = blockIdx.x * 256 + threadIdx.x;
    if (i < n) { counts[i] = 0; deg[i] = 1.0f; }
    if (i < 65536) {
        int c = i >> 7, k = i & 127;
        W1t[i] = f2bf(W1[k * 512 + c]);
    } else if (i < 131072) {
        int j = i - 65536;
        int c = j >> 9, k = j & 511;
        W2t[j] = f2bf(W2[k * 128 + c]);
    }
}

__global__ __launch_bounds__(256) void k_hist(const int* __restrict__ dst,
                                              const float* __restrict__ ew,
                                              int* __restrict__ counts,
                                              float* __restrict__ deg, int E) {
    int e = blockIdx.x * 256 + threadIdx.x;
    if (e < E) {
        int d = dst[e];
        atomicAdd(&counts[d], 1);
        atomicAdd(&deg[d], ew[e]);
    }
}

// Phase A: per-block (256 elems) exclusive scan into offsets, block sums out.
// Fused: deg -> dinv in place.
__global__ __launch_bounds__(256) void k_scanA(const int* __restrict__ counts,
                                               int* __restrict__ offsets,
                                               int* __restrict__ blockSum,
                                               float* __restrict__ deg, int n) {
    __shared__ int sdata[256];
    const int tid = threadIdx.x;
    const int i = blockIdx.x * 256 + tid;
    int c = (i < n) ? counts[i] : 0;
    sdata[tid] = c;
    __syncthreads();
#pragma unroll
    for (int off = 1; off < 256; off <<= 1) {
        int t = (tid >= off) ? sdata[tid - off] : 0;
        __syncthreads();
        sdata[tid] += t;
        __syncthreads();
    }
    if (i < n) offsets[i] = sdata[tid] - c;
    if (tid == 255) blockSum[blockIdx.x] = sdata[255];
    if (i < n) {
        float d = deg[i];
        deg[i] = (d > 0.f) ? rsqrtf(d) : 0.f;
    }
}

// Phase B: exclusive scan of <=256 block sums, in place.
__global__ __launch_bounds__(256) void k_scanB(int* __restrict__ blockSum, int nb) {
    __shared__ int sdata[256];
    const int tid = threadIdx.x;
    int v = (tid < nb) ? blockSum[tid] : 0;
    sdata[tid] = v;
    __syncthreads();
#pragma unroll
    for (int off = 1; off < 256; off <<= 1) {
        int t = (tid >= off) ? sdata[tid - off] : 0;
        __syncthreads();
        sdata[tid] += t;
        __syncthreads();
    }
    if (tid < nb) blockSum[tid] = sdata[tid] - v;
}

// Phase C: add block prefix to offsets.
__global__ __launch_bounds__(256) void k_scanC(int* __restrict__ offsets,
                                               const int* __restrict__ blockSum, int n) {
    const int i = blockIdx.x * 256 + threadIdx.x;
    if (i < n) offsets[i] += blockSum[blockIdx.x];
}

// scatter edges into dst-sorted slots. Bumps offsets[d] directly:
// post-scatter offsets[i] == end of node i's range (start = end - counts[i]).
__global__ __launch_bounds__(256) void k_scatter(const int* __restrict__ src,
                                                 const int* __restrict__ dst,
                                                 const float* __restrict__ ew,
                                                 const float* __restrict__ dinv,
                                                 int* __restrict__ offsets,
                                                 int2* __restrict__ sedge, int E) {
    int e = blockIdx.x * 256 + threadIdx.x;
    if (e >= E) return;
    int s = src[e];
    int d = dst[e];
    float coef = dinv[s] * ew[e] * dinv[d];
    int pos = atomicAdd(&offsets[d], 1);
    sedge[pos] = make_int2(s, __builtin_bit_cast(int, coef));
}

// ---------------- fused gather + MFMA MLP ----------------
// Block = 32 nodes, 4 waves. Phase 1: wave w gathers nodes [w*8, w*8+8),
// writes bf16 hi/lo to swizzled LDS. Phase 2: GEMM1 (A from LDS, hi/lo
// split), h to swizzled LDS. Phase 3: GEMM2, store out.
__global__ __launch_bounds__(256) void k_gmlp(const int* __restrict__ offsets,
                                              const int* __restrict__ counts,
                                              const int2* __restrict__ sedge,
                                              const float* __restrict__ dinv,
                                              const float* __restrict__ x,
                                              const short* __restrict__ W1t,
                                              const float* __restrict__ b1,
                                              const short* __restrict__ W2t,
                                              const float* __restrict__ b2,
                                              float* __restrict__ out, int n) {
    __shared__ __align__(16) short yhi[32 * 128];
    __shared__ __align__(16) short ylo[32 * 128];
    __shared__ __align__(16) short hlds[32 * 512];
    const int tid  = threadIdx.x;
    const int wave = tid >> 6;
    const int lane = tid & 63;
    const int l15  = lane & 15;
    const int lg   = lane >> 4;
    const int row0 = blockIdx.x * 32;
    const float2* x2 = (const float2*)x;

    // ---- phase 1: gather 8 nodes per wave, bf16 hi/lo -> swizzled LDS ----
    for (int i = 0; i < 8; ++i) {
        const int r = wave * 8 + i;        // row in tile
        const int node = row0 + r;
        float2 acc = make_float2(0.f, 0.f);
        if (node < n) {
            int o1 = offsets[node];        // post-scatter: end of range
            int o0 = o1 - counts[node];
            float di = dinv[node];
            float2 xv = x2[(size_t)node * 64 + lane];
            acc.x = di * di * xv.x;
            acc.y = di * di * xv.y;
            int j = o0;
            for (; j + 4 <= o1; j += 4) {
                int2 e0 = sedge[j], e1 = sedge[j + 1], e2 = sedge[j + 2], e3 = sedge[j + 3];
                float2 v0 = x2[(size_t)e0.x * 64 + lane];
                float2 v1 = x2[(size_t)e1.x * 64 + lane];
                float2 v2 = x2[(size_t)e2.x * 64 + lane];
                float2 v3 = x2[(size_t)e3.x * 64 + lane];
                float c0 = __builtin_bit_cast(float, e0.y);
                float c1 = __builtin_bit_cast(float, e1.y);
                float c2 = __builtin_bit_cast(float, e2.y);
                float c3 = __builtin_bit_cast(float, e3.y);
                acc.x = fmaf(c0, v0.x, acc.x); acc.y = fmaf(c0, v0.y, acc.y);
                acc.x = fmaf(c1, v1.x, acc.x); acc.y = fmaf(c1, v1.y, acc.y);
                acc.x = fmaf(c2, v2.x, acc.x); acc.y = fmaf(c2, v2.y, acc.y);
                acc.x = fmaf(c3, v3.x, acc.x); acc.y = fmaf(c3, v3.y, acc.y);
            }
            for (; j < o1; ++j) {
                int2 e = sedge[j];
                float2 v = x2[(size_t)e.x * 64 + lane];
                float c = __builtin_bit_cast(float, e.y);
                acc.x = fmaf(c, v.x, acc.x);
                acc.y = fmaf(c, v.y, acc.y);
            }
        }
        // hi/lo split; swizzle in 8-elem granules (XOR bits 3..5 of elem idx)
        short hx = f2bf(acc.x);
        short hy = f2bf(acc.y);
        short lx = f2bf(acc.x - bf2f(hx));
        short ly = f2bf(acc.y - bf2f(hy));
        const int e = (2 * lane) ^ ((r & 7) << 3);
        *(short2*)&yhi[r * 128 + e] = make_short2(hx, hy);
        *(short2*)&ylo[r * 128 + e] = make_short2(lx, ly);
    }
    __syncthreads();

    // ---- phase 2: GEMM1 h[32][512] = relu(y @ W1 + b1); wave cols cb1..+127
    const int cb1 = wave * 128;
    floatx4 acc[2][8];
#pragma unroll
    for (int m = 0; m < 2; ++m)
#pragma unroll
        for (int nn = 0; nn < 8; ++nn) acc[m][nn] = (floatx4)0.0f;

#pragma unroll
    for (int kk = 0; kk < 4; ++kk) {
        const int k0 = kk * 32 + lg * 8;
        short8v bf[8];
#pragma unroll
        for (int nn = 0; nn < 8; ++nn)
            bf[nn] = *(const short8v*)(W1t + (size_t)(cb1 + nn * 16 + l15) * 128 + k0);
#pragma unroll
        for (int m = 0; m < 2; ++m) {
            const int r = m * 16 + l15;
            const int ke = k0 ^ ((r & 7) << 3);
            short8v ahi = *(const short8v*)&yhi[r * 128 + ke];
            short8v alo = *(const short8v*)&ylo[r * 128 + ke];
#pragma unroll
            for (int nn = 0; nn < 8; ++nn)
                acc[m][nn] = __builtin_amdgcn_mfma_f32_16x16x32_bf16(ahi, bf[nn], acc[m][nn], 0, 0, 0);
#pragma unroll
            for (int nn = 0; nn < 8; ++nn)
                acc[m][nn] = __builtin_amdgcn_mfma_f32_16x16x32_bf16(alo, bf[nn], acc[m][nn], 0, 0, 0);
        }
    }

    // epilogue: bias + relu + bf16, swizzled LDS write
#pragma unroll
    for (int m = 0; m < 2; ++m)
#pragma unroll
        for (int nn = 0; nn < 8; ++nn) {
            const int c = cb1 + nn * 16 + l15;
            const float bb = b1[c];
#pragma unroll
            for (int i = 0; i < 4; ++i) {
                const int r = m * 16 + lg * 4 + i;
                float v = acc[m][nn][i] + bb;
                v = v > 0.f ? v : 0.f;
                hlds[r * 512 + (c ^ ((r & 7) << 3))] = f2bf(v);
            }
        }
    __syncthreads();

    // ---- phase 3: GEMM2 out[32][128] = relu(h @ W2 + b2); wave cols cb2..+31
    const int cb2 = wave * 32;
    floatx4 acc2[2][2];
#pragma unroll
    for (int m = 0; m < 2; ++m)
#pragma unroll
        for (int nn = 0; nn < 2; ++nn) acc2[m][nn] = (floatx4)0.0f;

#pragma unroll
    for (int kk = 0; kk < 16; ++kk) {
        const int k0 = kk * 32 + lg * 8;
        short8v bf2[2];
#pragma unroll
        for (int nn = 0; nn < 2; ++nn)
            bf2[nn] = *(const short8v*)(W2t + (size_t)(cb2 + nn * 16 + l15) * 512 + k0);
#pragma unroll
        for (int m = 0; m < 2; ++m) {
            const int r = m * 16 + l15;
            short8v a = *(const short8v*)&hlds[r * 512 + (k0 ^ ((r & 7) << 3))];
#pragma unroll
            for (int nn = 0; nn < 2; ++nn)
                acc2[m][nn] = __builtin_amdgcn_mfma_f32_16x16x32_bf16(a, bf2[nn], acc2[m][nn], 0, 0, 0);
        }
    }

#pragma unroll
    for (int m = 0; m < 2; ++m)
#pragma unroll
        for (int nn = 0; nn < 2; ++nn) {
            const int c = cb2 + nn * 16 + l15;
            const float bb = b2[c];
#pragma unroll
            for (int i = 0; i < 4; ++i) {
                const int rg = row0 + m * 16 + lg * 4 + i;
                if (rg < n) {
                    float v = acc2[m][nn][i] + bb;
                    out[(size_t)rg * 128 + c] = v > 0.f ? v : 0.f;
                }
            }
        }
}

extern "C" void kernel_launch(void* const* d_in, const int* in_sizes, int n_in,
                              void* d_out, int out_size, void* d_ws, size_t ws_size,
                              hipStream_t stream) {
    const float* x  = (const float*)d_in[0];
    const int*   ei = (const int*)d_in[1];
    const float* ew = (const float*)d_in[2];
    const float* W1 = (const float*)d_in[3];
    const float* b1 = (const float*)d_in[4];
    const float* W2 = (const float*)d_in[5];
    const float* b2 = (const float*)d_in[6];
    float* out = (float*)d_out;

    const int N = in_sizes[0] / 128;
    const int E = in_sizes[2];
    const int* src = ei;
    const int* dst = ei + E;
    const int NB = (N + 255) / 256;   // 196 for N=50000; k_scanB handles <=256

    // ws layout
    float* deg      = (float*)d_ws;            // N (becomes dinv)
    int*   counts   = (int*)(deg + N);         // N
    int*   offsets  = counts + N;              // N (becomes end-pointers post-scatter)
    int*   blockSum = offsets + N;             // 256
    int2*  sedge    = (int2*)((((uintptr_t)(blockSum + 256)) + 15) & ~(uintptr_t)15); // E
    short* W1t      = (short*)(sedge + E);     // 65536 bf16
    short* W2t      = W1t + 65536;             // 65536 bf16

    int nb;
    k_initprep<<<512, 256, 0, stream>>>(counts, deg, N, W1, W2, W1t, W2t);
    nb = (E + 255) / 256;
    k_hist<<<nb, 256, 0, stream>>>(dst, ew, counts, deg, E);
    k_scanA<<<NB, 256, 0, stream>>>(counts, offsets, blockSum, deg, N);
    k_scanB<<<1, 256, 0, stream>>>(blockSum, NB);
    k_scanC<<<NB, 256, 0, stream>>>(offsets, blockSum, N);
    nb = (E + 255) / 256;
    k_scatter<<<nb, 256, 0, stream>>>(src, dst, ew, deg, offsets, sedge, E);
    nb = (N + 31) / 32;
    k_gmlp<<<nb, 256, 0, stream>>>(offsets, counts, sedge, deg, x,
                                   W1t, b1, W2t, b2, out, N);
}

// Round 7
// 283.866 us; speedup vs baseline: 1.1149x; 1.1149x over previous
//
#include <hip/hip_runtime.h>
#include <math.h>

// GCN 2-layer: out = relu( relu( (A @ x) @ W1 + b1 ) @ W2 + b2 )
// A = D^-1/2 (Adj + I) D^-1/2 (weighted, self-loop weight 1).
// Aggregation at d_in=128 ((A@x)@W1 == A@(x@W1), linearity).
// R7: un-fuse gather (R6 fusion lost TLP); x pre-converted to bf16
// (halves gather fetch); y stored as single bf16 plane in MFMA A-layout
// (halves GEMM1 MFMA, removes all cvt from mlp). Error budget: measured
// 0.0078 with y~f32; y/x-bf16 quant ~doubles it -> ~0.015 vs thr 0.042.

typedef __attribute__((ext_vector_type(8))) short short8v;   // 8 bf16 = 4 VGPR
typedef __attribute__((ext_vector_type(4))) float floatx4;   // MFMA C/D

__device__ __forceinline__ short f2bf(float f) {             // RNE f32->bf16
    unsigned u = __builtin_bit_cast(unsigned, f);
    unsigned r = (u + 0x7FFFu + ((u >> 16) & 1u)) >> 16;
    return (short)r;
}
__device__ __forceinline__ float bfu_lo(unsigned u) {        // packed pair -> f32
    return __builtin_bit_cast(float, u << 16);
}
__device__ __forceinline__ float bfu_hi(unsigned u) {
    return __builtin_bit_cast(float, u & 0xFFFF0000u);
}

// ---------------- init + weight prep + x->bf16 (merged) ----------------
__global__ __launch_bounds__(256) void k_initprep(int* __restrict__ counts,
                                                  float* __restrict__ deg, int n,
                                                  const float* __restrict__ W1,
                                                  const float* __restrict__ W2,
                                                  short* __restrict__ W1t,
                                                  short* __restrict__ W2t,
                                                  const float* __restrict__ x,
                                                  short* __restrict__ xbf) {
    int i = blockIdx.x * 256 + threadIdx.x;
    int nx4 = n * 32;                       // n*128 / 4
    if (i < nx4) {                          // x -> bf16, 4 elems/thread
        float4 v = ((const float4*)x)[i];
        short4 s;
        s.x = f2bf(v.x); s.y = f2bf(v.y); s.z = f2bf(v.z); s.w = f2bf(v.w);
        *(short4*)&xbf[(size_t)i * 4] = s;
    }
    if (i < n) { counts[i] = 0; deg[i] = 1.0f; }
    if (i < 65536) {
        int c = i >> 7, k = i & 127;
        W1t[i] = f2bf(W1[k * 512 + c]);
    } else if (i < 131072) {
        int j = i - 65536;
        int c = j >> 9, k = j & 511;
        W2t[j] = f2bf(W2[k * 128 + c]);
    }
}

__global__ __launch_bounds__(256) void k_hist(const int* __restrict__ dst,
                                              const float* __restrict__ ew,
                                              int* __restrict__ counts,
                                              float* __restrict__ deg, int E) {
    int e = blockIdx.x * 256 + threadIdx.x;
    if (e < E) {
        int d = dst[e];
        atomicAdd(&counts[d], 1);
        atomicAdd(&deg[d], ew[e]);
    }
}

// Phase A: per-block exclusive scan into offsets, block sums out; deg->dinv.
__global__ __launch_bounds__(256) void k_scanA(const int* __restrict__ counts,
                                               int* __restrict__ offsets,
                                               int* __restrict__ blockSum,
                                               float* __restrict__ deg, int n) {
    __shared__ int sdata[256];
    const int tid = threadIdx.x;
    const int i = blockIdx.x * 256 + tid;
    int c = (i < n) ? counts[i] : 0;
    sdata[tid] = c;
    __syncthreads();
#pragma unroll
    for (int off = 1; off < 256; off <<= 1) {
        int t = (tid >= off) ? sdata[tid - off] : 0;
        __syncthreads();
        sdata[tid] += t;
        __syncthreads();
    }
    if (i < n) offsets[i] = sdata[tid] - c;
    if (tid == 255) blockSum[blockIdx.x] = sdata[255];
    if (i < n) {
        float d = deg[i];
        deg[i] = (d > 0.f) ? rsqrtf(d) : 0.f;
    }
}

__global__ __launch_bounds__(256) void k_scanB(int* __restrict__ blockSum, int nb) {
    __shared__ int sdata[256];
    const int tid = threadIdx.x;
    int v = (tid < nb) ? blockSum[tid] : 0;
    sdata[tid] = v;
    __syncthreads();
#pragma unroll
    for (int off = 1; off < 256; off <<= 1) {
        int t = (tid >= off) ? sdata[tid - off] : 0;
        __syncthreads();
        sdata[tid] += t;
        __syncthreads();
    }
    if (tid < nb) blockSum[tid] = sdata[tid] - v;
}

__global__ __launch_bounds__(256) void k_scanC(int* __restrict__ offsets,
                                               const int* __restrict__ blockSum, int n) {
    const int i = blockIdx.x * 256 + threadIdx.x;
    if (i < n) offsets[i] += blockSum[blockIdx.x];
}

// scatter edges into dst-sorted slots; bumps offsets[d] (post: end of range).
__global__ __launch_bounds__(256) void k_scatter(const int* __restrict__ src,
                                                 const int* __restrict__ dst,
                                                 const float* __restrict__ ew,
                                                 const float* __restrict__ dinv,
                                                 int* __restrict__ offsets,
                                                 int2* __restrict__ sedge, int E) {
    int e = blockIdx.x * 256 + threadIdx.x;
    if (e >= E) return;
    int s = src[e];
    int d = dst[e];
    float coef = dinv[s] * ew[e] * dinv[d];
    int pos = atomicAdd(&offsets[d], 1);
    sedge[pos] = make_int2(s, __builtin_bit_cast(int, coef));
}

// pull gather (bf16 x): one wave per node, 4B/lane loads, f32 accumulate,
// bf16 y out. ybf[node][128] is directly the MFMA A layout (row-major).
__global__ __launch_bounds__(256) void k_gather(const int* __restrict__ offsets,
                                                const int* __restrict__ counts,
                                                const int2* __restrict__ sedge,
                                                const float* __restrict__ dinv,
                                                const unsigned* __restrict__ xbf_u,
                                                unsigned* __restrict__ ybf_u, int n) {
    int wid = (blockIdx.x * 256 + threadIdx.x) >> 6;
    if (wid >= n) return;
    int lane = threadIdx.x & 63;
    int o1 = offsets[wid];               // post-scatter: end of range
    int o0 = o1 - counts[wid];
    float di = dinv[wid];
    unsigned xs = xbf_u[(size_t)wid * 64 + lane];
    float2 acc;
    acc.x = di * di * bfu_lo(xs);
    acc.y = di * di * bfu_hi(xs);
    int j = o0;
    for (; j + 4 <= o1; j += 4) {
        int2 e0 = sedge[j], e1 = sedge[j + 1], e2 = sedge[j + 2], e3 = sedge[j + 3];
        unsigned v0 = xbf_u[(size_t)e0.x * 64 + lane];
        unsigned v1 = xbf_u[(size_t)e1.x * 64 + lane];
        unsigned v2 = xbf_u[(size_t)e2.x * 64 + lane];
        unsigned v3 = xbf_u[(size_t)e3.x * 64 + lane];
        float c0 = __builtin_bit_cast(float, e0.y);
        float c1 = __builtin_bit_cast(float, e1.y);
        float c2 = __builtin_bit_cast(float, e2.y);
        float c3 = __builtin_bit_cast(float, e3.y);
        acc.x = fmaf(c0, bfu_lo(v0), acc.x); acc.y = fmaf(c0, bfu_hi(v0), acc.y);
        acc.x = fmaf(c1, bfu_lo(v1), acc.x); acc.y = fmaf(c1, bfu_hi(v1), acc.y);
        acc.x = fmaf(c2, bfu_lo(v2), acc.x); acc.y = fmaf(c2, bfu_hi(v2), acc.y);
        acc.x = fmaf(c3, bfu_lo(v3), acc.x); acc.y = fmaf(c3, bfu_hi(v3), acc.y);
    }
    for (; j < o1; ++j) {
        int2 e = sedge[j];
        unsigned v = xbf_u[(size_t)e.x * 64 + lane];
        float c = __builtin_bit_cast(float, e.y);
        acc.x = fmaf(c, bfu_lo(v), acc.x);
        acc.y = fmaf(c, bfu_hi(v), acc.y);
    }
    unsigned lo = (unsigned)(unsigned short)f2bf(acc.x);
    unsigned hi = (unsigned)(unsigned short)f2bf(acc.y);
    ybf_u[(size_t)wid * 64 + lane] = lo | (hi << 16);
}

// ---------------- MFMA MLP (bf16 y in, no cvt on A path) ----------------
// 32 rows/block, 4 waves. GEMM1: wave w -> h cols [w*128,+128); A direct
// short8v global loads from ybf. GEMM2: wave w -> out cols [w*32,+32);
// h in XOR-swizzled bf16 LDS (32KB).
__global__ __launch_bounds__(256) void k_mlp(const short* __restrict__ ybf,
                                             const short* __restrict__ W1t,
                                             const float* __restrict__ b1,
                                             const short* __restrict__ W2t,
                                             const float* __restrict__ b2,
                                             float* __restrict__ out, int n) {
    __shared__ __align__(16) short hlds[32 * 512];
    const int tid  = threadIdx.x;
    const int wave = tid >> 6;
    const int lane = tid & 63;
    const int l15  = lane & 15;
    const int lg   = lane >> 4;
    const int row0 = blockIdx.x * 32;

    const int cb1 = wave * 128;
    floatx4 acc[2][8];
#pragma unroll
    for (int m = 0; m < 2; ++m)
#pragma unroll
        for (int nn = 0; nn < 8; ++nn) acc[m][nn] = (floatx4)0.0f;

#pragma unroll
    for (int kk = 0; kk < 4; ++kk) {
        const int k0 = kk * 32 + lg * 8;
        short8v bf[8];
#pragma unroll
        for (int nn = 0; nn < 8; ++nn)
            bf[nn] = *(const short8v*)(W1t + (size_t)(cb1 + nn * 16 + l15) * 128 + k0);
#pragma unroll
        for (int m = 0; m < 2; ++m) {
            short8v a = *(const short8v*)(ybf + (size_t)(row0 + m * 16 + l15) * 128 + k0);
#pragma unroll
            for (int nn = 0; nn < 8; ++nn)
                acc[m][nn] = __builtin_amdgcn_mfma_f32_16x16x32_bf16(a, bf[nn], acc[m][nn], 0, 0, 0);
        }
    }

    // epilogue: bias + relu + bf16, swizzled LDS write
#pragma unroll
    for (int m = 0; m < 2; ++m)
#pragma unroll
        for (int nn = 0; nn < 8; ++nn) {
            const int c = cb1 + nn * 16 + l15;
            const float bb = b1[c];
#pragma unroll
            for (int i = 0; i < 4; ++i) {
                const int r = m * 16 + lg * 4 + i;
                float v = acc[m][nn][i] + bb;
                v = v > 0.f ? v : 0.f;
                hlds[r * 512 + (c ^ ((r & 7) << 3))] = f2bf(v);
            }
        }
    __syncthreads();

    const int cb2 = wave * 32;
    floatx4 acc2[2][2];
#pragma unroll
    for (int m = 0; m < 2; ++m)
#pragma unroll
        for (int nn = 0; nn < 2; ++nn) acc2[m][nn] = (floatx4)0.0f;

#pragma unroll
    for (int kk = 0; kk < 16; ++kk) {
        const int k0 = kk * 32 + lg * 8;
        short8v bf2[2];
#pragma unroll
        for (int nn = 0; nn < 2; ++nn)
            bf2[nn] = *(const short8v*)(W2t + (size_t)(cb2 + nn * 16 + l15) * 512 + k0);
#pragma unroll
        for (int m = 0; m < 2; ++m) {
            const int r = m * 16 + l15;
            short8v a = *(const short8v*)&hlds[r * 512 + (k0 ^ ((r & 7) << 3))];
#pragma unroll
            for (int nn = 0; nn < 2; ++nn)
                acc2[m][nn] = __builtin_amdgcn_mfma_f32_16x16x32_bf16(a, bf2[nn], acc2[m][nn], 0, 0, 0);
        }
    }

#pragma unroll
    for (int m = 0; m < 2; ++m)
#pragma unroll
        for (int nn = 0; nn < 2; ++nn) {
            const int c = cb2 + nn * 16 + l15;
            const float bb = b2[c];
#pragma unroll
            for (int i = 0; i < 4; ++i) {
                const int rg = row0 + m * 16 + lg * 4 + i;
                if (rg < n) {
                    float v = acc2[m][nn][i] + bb;
                    out[(size_t)rg * 128 + c] = v > 0.f ? v : 0.f;
                }
            }
        }
}

extern "C" void kernel_launch(void* const* d_in, const int* in_sizes, int n_in,
                              void* d_out, int out_size, void* d_ws, size_t ws_size,
                              hipStream_t stream) {
    const float* x  = (const float*)d_in[0];
    const int*   ei = (const int*)d_in[1];
    const float* ew = (const float*)d_in[2];
    const float* W1 = (const float*)d_in[3];
    const float* b1 = (const float*)d_in[4];
    const float* W2 = (const float*)d_in[5];
    const float* b2 = (const float*)d_in[6];
    float* out = (float*)d_out;

    const int N = in_sizes[0] / 128;
    const int E = in_sizes[2];
    const int* src = ei;
    const int* dst = ei + E;
    const int NB = (N + 255) / 256;          // scan blocks (<=256 for scanB)
    const int NBM = (N + 31) / 32;           // mlp blocks
    const int NROWS = NBM * 32;              // padded rows for ybf

    // ws layout
    float* deg      = (float*)d_ws;            // N (becomes dinv)
    int*   counts   = (int*)(deg + N);         // N
    int*   offsets  = counts + N;              // N (end-pointers post-scatter)
    int*   blockSum = offsets + N;             // 256
    int2*  sedge    = (int2*)((((uintptr_t)(blockSum + 256)) + 15) & ~(uintptr_t)15); // E
    short* W1t      = (short*)(sedge + E);     // 65536 bf16
    short* W2t      = W1t + 65536;             // 65536 bf16
    short* xbf      = (short*)((((uintptr_t)(W2t + 65536)) + 15) & ~(uintptr_t)15);   // N*128
    short* ybf      = xbf + (size_t)N * 128;   // NROWS*128 (tail rows unwritten; out guarded)

    int nb;
    nb = (N * 32 + 255) / 256;   // covers x-cvt (n*32 threads) and all smaller ranges
    k_initprep<<<nb, 256, 0, stream>>>(counts, deg, N, W1, W2, W1t, W2t, x, xbf);
    nb = (E + 255) / 256;
    k_hist<<<nb, 256, 0, stream>>>(dst, ew, counts, deg, E);
    k_scanA<<<NB, 256, 0, stream>>>(counts, offsets, blockSum, deg, N);
    k_scanB<<<1, 256, 0, stream>>>(blockSum, NB);
    k_scanC<<<NB, 256, 0, stream>>>(offsets, blockSum, N);
    nb = (E + 255) / 256;
    k_scatter<<<nb, 256, 0, stream>>>(src, dst, ew, deg, offsets, sedge, E);
    nb = (N * 64 + 255) / 256;   // one wave per node
    k_gather<<<nb, 256, 0, stream>>>(offsets, counts, sedge, deg,
                                     (const unsigned*)xbf, (unsigned*)ybf, N);
    k_mlp<<<NBM, 256, 0, stream>>>(ybf, W1t, b1, W2t, b2, out, N);
}